// Round 9
// baseline (5027.288 us; speedup 1.0000x reference)
//
#include <hip/hip_runtime.h>
#include <hip/hip_fp16.h>

// Problem dims
#define H     1024
#define NIN   128
#define NOUT  128
#define BATCH 64
#define SEQ   512
#define MROWS (BATCH * SEQ)   // 32768

// Fused-scan decomposition
#define NCLUST 8
#define GB     8
#define UNITS  4096   // 8 rows x 1024 halfs / 2 halfs per unit
#define D0     4      // h0 ring depth (L1 lags L0)
#define D1     2      // h1 ring depth

typedef _Float16 half8  __attribute__((ext_vector_type(8)));
typedef _Float16 half4v __attribute__((ext_vector_type(4)));
typedef float    f32x4  __attribute__((ext_vector_type(4)));
typedef unsigned uint4v __attribute__((ext_vector_type(4)));
typedef unsigned long long u64;

// ---------------------------------------------------------------------------
__global__ void cvt16_kernel(const float* __restrict__ src,
                             _Float16* __restrict__ dst, int n4) {
  int i = blockIdx.x * blockDim.x + threadIdx.x;
  if (i < n4) {
    float4 v = reinterpret_cast<const float4*>(src)[i];
    half4v h = {(_Float16)v.x, (_Float16)v.y, (_Float16)v.z, (_Float16)v.w};
    *reinterpret_cast<half4v*>(dst + (size_t)i * 4) = h;
  }
}

// ---------------------------------------------------------------------------
__global__ void init_misc_kernel(const float* __restrict__ b_ih0,
                                 const float* __restrict__ b_hh0,
                                 const float* __restrict__ b_ih1,
                                 const float* __restrict__ b_hh1,
                                 float* __restrict__ bias0,
                                 float* __restrict__ bias1,
                                 unsigned* __restrict__ zero_base,
                                 int zero_words) {
  int i = blockIdx.x * blockDim.x + threadIdx.x;
  if (i < H) {
    bias0[i] = b_ih0[i] + b_hh0[i];
    bias1[i] = b_ih1[i] + b_hh1[i];
  }
  for (int j = i; j < zero_words; j += gridDim.x * blockDim.x) zero_base[j] = 0u;
}

// ---------------------------------------------------------------------------
// Fused two-layer recurrent scan. Blocks 0..127 = L0, 128..255 = L1.
// 8 clusters x GB=8 batch rows; per role 16 WGs/cluster x 64 cols/WG.
// Protocol / layout / gating identical to R8 (analysis-verified); R9 changes
// are resource-level only: __launch_bounds__(256,2) caps VGPR at 256 (R8's
// ~400-VGPR L1 path is the prime launch/alloc-failure suspect), L1 polls the
// two rings sequentially (8 live quads, not 16), and L1's Wih1 is un-pinned
// (compiler remats from the L2-resident slice under the cap).
//
// Unit w = kt*128 + hh*64 + r*8 + g*2 + q encodes h[r][kt*32+g*8+hh*4+q*2+b],
// LDS granule u (byte 8u) = ring pair u; fragment (r,g,kt) = 2x ds_read_b64
// at kt*512 + {0,256} + r*32 + g*8 (2 lines/bank = conflict-free).
// ---------------------------------------------------------------------------
__global__ __launch_bounds__(256, 2) void fused_scan_kernel(
    const _Float16* __restrict__ x16,   // [B][S][NIN] f16
    const _Float16* __restrict__ Wih0,  // [H][NIN]
    const _Float16* __restrict__ Whh0,  // [H][H]
    const _Float16* __restrict__ Wih1,  // [H][H]
    const _Float16* __restrict__ Whh1,  // [H][H]
    const float* __restrict__ bias0,
    const float* __restrict__ bias1,
    u64* __restrict__ f0, u64* __restrict__ s0,   // h0 rings [NCLUST][D0][UNITS]
    u64* __restrict__ f1, u64* __restrict__ s1,   // h1 rings [NCLUST][D1][UNITS]
    unsigned* __restrict__ progress,              // [NCLUST][64] (zeroed)
    float* __restrict__ h_last)                   // [BATCH][H] f32
{
  __shared__ unsigned ldsA[UNITS];   // 16KB: h0 (both roles)
  __shared__ unsigned ldsB[UNITS];   // 16KB: h1 (L1 only)

  const int blk = blockIdx.x;
  const bool isL1 = blk >= 128;
  const int j = isL1 ? blk - 128 : blk;
  const int cluster = j & (NCLUST - 1);
  const int rank = j >> 3;             // 0..15
  const int tid = threadIdx.x;
  const int lane = tid & 63;
  const int wave = tid >> 6;
  const int fr = lane & 15;
  const int g = lane >> 4;
  const int kg8 = g * 8;
  const int wcol = rank * 64 + wave * 16;
  const int c0 = wcol + g * 4;
  const int rb = lane & 15;
  const int rb8 = rb & 7;
  const bool act = rb < GB;
  const int b0 = cluster * GB;

  // Pinned weights: L0 = Whh0(128)+Wih0(16); L1 = Whh1(128). L1's Wih1 is
  // deliberately NOT pinned (remat from L2 under the 256-VGPR cap).
  f32x4 wA[32], wB0[4];
  const _Float16* wih1_row = Wih1 + (size_t)(wcol + fr) * H;
  if (!isL1) {
#pragma unroll
    for (int kt = 0; kt < 32; ++kt) {
      wA[kt] = *reinterpret_cast<const f32x4*>(
          &Whh0[(size_t)(wcol + fr) * H + kt * 32 + kg8]);
      asm volatile("" : "+v"(wA[kt]));
    }
#pragma unroll
    for (int kt = 0; kt < 4; ++kt) {
      wB0[kt] = *reinterpret_cast<const f32x4*>(
          &Wih0[(size_t)(wcol + fr) * NIN + kt * 32 + kg8]);
      asm volatile("" : "+v"(wB0[kt]));
    }
  } else {
#pragma unroll
    for (int kt = 0; kt < 32; ++kt) {
      wA[kt] = *reinterpret_cast<const f32x4*>(
          &Whh1[(size_t)(wcol + fr) * H + kt * 32 + kg8]);
      asm volatile("" : "+v"(wA[kt]));
    }
  }

  u64* f0c = f0 + (size_t)cluster * (D0 * UNITS);
  u64* s0c = s0 + (size_t)cluster * (D0 * UNITS);
  u64* f1c = f1 + (size_t)cluster * (D1 * UNITS);
  u64* s1c = s1 + (size_t)cluster * (D1 * UNITS);

  // producer unit pair {w0, w0+1}
  const int w0 = (c0 >> 5) * 128 + (((c0 >> 2) & 1) << 6) + rb * 8 +
                 (((c0 >> 3) & 3) << 1);

  const f32x4 bv = *reinterpret_cast<const f32x4*>(
      (isL1 ? bias1 : bias0) + c0);

  f32x4 xf[4] = {};
  if (!isL1 && act) {
#pragma unroll
    for (int kt = 0; kt < 4; ++kt)
      xf[kt] = *reinterpret_cast<const f32x4*>(
          &x16[((size_t)(b0 + rb) * SEQ + 0) * NIN + kt * 32 + kg8]);
  }

  for (int t = 0; t < SEQ; ++t) {
    if (!isL1) {
      // ======================= L0 =======================
      uint4v q[8];
      if (t > 0) {
        const unsigned tag = (unsigned)t;   // h0(t-1)
        const char* fb = (const char*)(f0c + (size_t)((t - 1) & 3) * UNITS) +
                         (size_t)tid * 16;
        const char* sb = (const char*)(s0c + (size_t)((t - 1) & 3) * UNITS) +
                         (size_t)tid * 16;
        int it = 0;
        while (true) {
          if (it < 4) {
#pragma unroll
            for (int jj = 0; jj < 8; ++jj)
              asm volatile("global_load_dwordx4 %0, %1, off sc0 nt"
                           : "=&v"(q[jj]) : "v"(fb + jj * 4096) : "memory");
          } else {
#pragma unroll
            for (int jj = 0; jj < 8; ++jj)
              asm volatile("global_load_dwordx4 %0, %1, off sc0 sc1"
                           : "=&v"(q[jj]) : "v"(sb + jj * 4096) : "memory");
          }
          asm volatile("s_waitcnt vmcnt(0)" ::: "memory");
          bool ok = true;
#pragma unroll
          for (int jj = 0; jj < 8; ++jj)
            ok &= (q[jj].y == tag) & (q[jj].w == tag);
          if (__ballot(ok) == ~0ull) break;
          ++it;
          if (it > 4) __builtin_amdgcn_s_sleep(1);
        }
      }
      // anti-overwrite gate: L1 done with h0(t-4)
      if (t >= 4) {
        const unsigned need = (unsigned)(t - 3);
        while (true) {
          unsigned pv = need;
          if (lane < 16)
            pv = __hip_atomic_load(&progress[cluster * 64 + lane],
                                   __ATOMIC_RELAXED, __HIP_MEMORY_SCOPE_SYSTEM);
          if (__ballot(pv >= need) == ~0ull) break;
          __builtin_amdgcn_s_sleep(1);
        }
      }
      f32x4 xfn[4] = {};
      if (act) {
        int t2 = (t + 1 < SEQ) ? (t + 1) : t;
#pragma unroll
        for (int kt = 0; kt < 4; ++kt)
          xfn[kt] = *reinterpret_cast<const f32x4*>(
              &x16[((size_t)(b0 + rb) * SEQ + t2) * NIN + kt * 32 + kg8]);
      }

      f32x4 acc[8] = {};
      if (t > 0) {
        __syncthreads();
#pragma unroll
        for (int jj = 0; jj < 8; ++jj) {
          u64 pk = (u64)q[jj].x | ((u64)q[jj].z << 32);
          *reinterpret_cast<u64*>((char*)ldsA + 8 * tid + 2048 * jj) = pk;
        }
        __syncthreads();
        const char* lb = (const char*)ldsA;
#pragma unroll
        for (int kt = 0; kt < 32; ++kt) {
          union { u64 v[2]; half8 h; } u;
          u.v[0] = *reinterpret_cast<const u64*>(lb + kt * 512 + rb8 * 32 + g * 8);
          u.v[1] = *reinterpret_cast<const u64*>(lb + kt * 512 + 256 + rb8 * 32 + g * 8);
          acc[kt & 3] = __builtin_amdgcn_mfma_f32_16x16x32_f16(
              __builtin_bit_cast(half8, wA[kt]), u.h, acc[kt & 3], 0, 0, 0);
        }
      }
#pragma unroll
      for (int kt = 0; kt < 4; ++kt)
        acc[4 + kt] = __builtin_amdgcn_mfma_f32_16x16x32_f16(
            __builtin_bit_cast(half8, wB0[kt]), __builtin_bit_cast(half8, xf[kt]),
            acc[4 + kt], 0, 0, 0);
      f32x4 s = ((acc[0] + acc[1]) + (acc[2] + acc[3])) +
                ((acc[4] + acc[5]) + (acc[6] + acc[7])) + bv;

      if (act) {
        union { u64 u; _Float16 h[4]; unsigned w[2]; } pk;
#pragma unroll
        for (int r = 0; r < 4; ++r) {
          float v = fminf(fmaxf(s[r], -15.f), 15.f);
          float e = __expf(2.f * v);
          pk.h[r] = (_Float16)(1.f - 2.f * __builtin_amdgcn_rcpf(e + 1.f));
        }
        const unsigned tagw = (unsigned)(t + 1);
        uint4v sv = {pk.w[0], tagw, pk.w[1], tagw};
        u64* fdst = f0c + (size_t)(t & 3) * UNITS + w0;
        u64* sdst = s0c + (size_t)(t & 3) * UNITS + w0;
        asm volatile(
            "global_store_dwordx4 %0, %2, off sc0\n\t"
            "global_store_dwordx4 %1, %2, off sc0 sc1"
            :: "v"(fdst), "v"(sdst), "v"(sv) : "memory");
      }
#pragma unroll
      for (int kt = 0; kt < 4; ++kt) xf[kt] = xfn[kt];
    } else {
      // ======================= L1 =======================
      uint4v q[8];
      // ---- poll h0(t): tag t+1 in slot t&3 ----
      {
        const unsigned tagA = (unsigned)(t + 1);
        const char* fbA = (const char*)(f0c + (size_t)(t & 3) * UNITS) +
                          (size_t)tid * 16;
        const char* sbA = (const char*)(s0c + (size_t)(t & 3) * UNITS) +
                          (size_t)tid * 16;
        int it = 0;
        while (true) {
          if (it < 4) {
#pragma unroll
            for (int jj = 0; jj < 8; ++jj)
              asm volatile("global_load_dwordx4 %0, %1, off sc0 nt"
                           : "=&v"(q[jj]) : "v"(fbA + jj * 4096) : "memory");
          } else {
#pragma unroll
            for (int jj = 0; jj < 8; ++jj)
              asm volatile("global_load_dwordx4 %0, %1, off sc0 sc1"
                           : "=&v"(q[jj]) : "v"(sbA + jj * 4096) : "memory");
          }
          asm volatile("s_waitcnt vmcnt(0)" ::: "memory");
          bool ok = true;
#pragma unroll
          for (int jj = 0; jj < 8; ++jj)
            ok &= (q[jj].y == tagA) & (q[jj].w == tagA);
          if (__ballot(ok) == ~0ull) break;
          ++it;
          if (it > 4) __builtin_amdgcn_s_sleep(1);
        }
      }
      __syncthreads();   // prior step's LDS fragment reads retired
#pragma unroll
      for (int jj = 0; jj < 8; ++jj) {
        u64 pk = (u64)q[jj].x | ((u64)q[jj].z << 32);
        *reinterpret_cast<u64*>((char*)ldsA + 8 * tid + 2048 * jj) = pk;
      }
      // ---- poll h1(t-1): tag t in slot (t-1)&1 (q regs reused) ----
      if (t > 0) {
        const unsigned tagB = (unsigned)t;
        const char* fbB = (const char*)(f1c + (size_t)((t - 1) & 1) * UNITS) +
                          (size_t)tid * 16;
        const char* sbB = (const char*)(s1c + (size_t)((t - 1) & 1) * UNITS) +
                          (size_t)tid * 16;
        int it = 0;
        while (true) {
          if (it < 4) {
#pragma unroll
            for (int jj = 0; jj < 8; ++jj)
              asm volatile("global_load_dwordx4 %0, %1, off sc0 nt"
                           : "=&v"(q[jj]) : "v"(fbB + jj * 4096) : "memory");
          } else {
#pragma unroll
            for (int jj = 0; jj < 8; ++jj)
              asm volatile("global_load_dwordx4 %0, %1, off sc0 sc1"
                           : "=&v"(q[jj]) : "v"(sbB + jj * 4096) : "memory");
          }
          asm volatile("s_waitcnt vmcnt(0)" ::: "memory");
          bool ok = true;
#pragma unroll
          for (int jj = 0; jj < 8; ++jj)
            ok &= (q[jj].y == tagB) & (q[jj].w == tagB);
          if (__ballot(ok) == ~0ull) break;
          ++it;
          if (it > 4) __builtin_amdgcn_s_sleep(1);
        }
#pragma unroll
        for (int jj = 0; jj < 8; ++jj) {
          u64 pk = (u64)q[jj].x | ((u64)q[jj].z << 32);
          *reinterpret_cast<u64*>((char*)ldsB + 8 * tid + 2048 * jj) = pk;
        }
      }
      __syncthreads();

      f32x4 acc[8] = {};
      const char* lbA = (const char*)ldsA;
      const char* lbB = (const char*)ldsB;
#pragma unroll
      for (int kt = 0; kt < 32; ++kt) {
        // Wih1 fragment: un-pinned, compiler loads from L2-resident slice
        f32x4 wb = *reinterpret_cast<const f32x4*>(&wih1_row[kt * 32 + kg8]);
        union { u64 v[2]; half8 h; } u0;
        u0.v[0] = *reinterpret_cast<const u64*>(lbA + kt * 512 + rb8 * 32 + g * 8);
        u0.v[1] = *reinterpret_cast<const u64*>(lbA + kt * 512 + 256 + rb8 * 32 + g * 8);
        acc[4 + (kt & 3)] = __builtin_amdgcn_mfma_f32_16x16x32_f16(
            __builtin_bit_cast(half8, wb), u0.h, acc[4 + (kt & 3)], 0, 0, 0);
        if (t > 0) {
          union { u64 v[2]; half8 h; } u1;
          u1.v[0] = *reinterpret_cast<const u64*>(lbB + kt * 512 + rb8 * 32 + g * 8);
          u1.v[1] = *reinterpret_cast<const u64*>(lbB + kt * 512 + 256 + rb8 * 32 + g * 8);
          acc[kt & 3] = __builtin_amdgcn_mfma_f32_16x16x32_f16(
              __builtin_bit_cast(half8, wA[kt]), u1.h, acc[kt & 3], 0, 0, 0);
        }
      }
      f32x4 s = ((acc[0] + acc[1]) + (acc[2] + acc[3])) +
                ((acc[4] + acc[5]) + (acc[6] + acc[7])) + bv;

      if (act) {
        union { u64 u; _Float16 h[4]; unsigned w[2]; } pk;
        float hv[4];
#pragma unroll
        for (int r = 0; r < 4; ++r) {
          float v = fminf(fmaxf(s[r], -15.f), 15.f);
          float e = __expf(2.f * v);
          hv[r] = 1.f - 2.f * __builtin_amdgcn_rcpf(e + 1.f);
          pk.h[r] = (_Float16)hv[r];
        }
        if (t < SEQ - 1) {
          const unsigned tagw = (unsigned)(t + 1);
          uint4v sv = {pk.w[0], tagw, pk.w[1], tagw};
          u64* fdst = f1c + (size_t)(t & 1) * UNITS + w0;
          u64* sdst = s1c + (size_t)(t & 1) * UNITS + w0;
          asm volatile(
              "global_store_dwordx4 %0, %2, off sc0\n\t"
              "global_store_dwordx4 %1, %2, off sc0 sc1"
              :: "v"(fdst), "v"(sdst), "v"(sv) : "memory");
        } else {
          float4 o = {hv[0], hv[1], hv[2], hv[3]};
          *reinterpret_cast<float4*>(&h_last[(size_t)(b0 + rb) * H + c0]) = o;
        }
      }
      if (tid == 0)
        __hip_atomic_store(&progress[cluster * 64 + rank], (unsigned)(t + 1),
                           __ATOMIC_RELAXED, __HIP_MEMORY_SCOPE_SYSTEM);
    }
  }
}

// ---------------------------------------------------------------------------
__global__ __launch_bounds__(256) void fc_kernel(
    const float* __restrict__ h_last, const float* __restrict__ W_fc,
    const float* __restrict__ b_fc, float* __restrict__ out) {
  const int wave = threadIdx.x >> 6, lane = threadIdx.x & 63;
  const int o = blockIdx.x * 4 + wave;  // 0..8191
  const int b = o >> 7, n = o & 127;
  const float* hr = h_last + (size_t)b * H;
  const float* wr = W_fc + (size_t)n * H;
  float s = 0.0f;
  for (int k = lane; k < H; k += 64) s += hr[k] * wr[k];
#pragma unroll
  for (int off = 32; off; off >>= 1) s += __shfl_down(s, off);
  if (lane == 0) out[o] = s + b_fc[n];
}

// ---------------------------------------------------------------------------
extern "C" void kernel_launch(void* const* d_in, const int* in_sizes, int n_in,
                              void* d_out, int out_size, void* d_ws,
                              size_t ws_size, hipStream_t stream) {
  (void)in_sizes; (void)n_in; (void)out_size; (void)ws_size;
  const float* x     = (const float*)d_in[0];
  const float* W_ih0 = (const float*)d_in[1];
  const float* b_ih0 = (const float*)d_in[2];
  const float* W_hh0 = (const float*)d_in[3];
  const float* b_hh0 = (const float*)d_in[4];
  const float* W_ih1 = (const float*)d_in[5];
  const float* b_ih1 = (const float*)d_in[6];
  const float* W_hh1 = (const float*)d_in[7];
  const float* b_hh1 = (const float*)d_in[8];
  const float* W_fc  = (const float*)d_in[9];
  const float* b_fc  = (const float*)d_in[10];
  float* out = (float*)d_out;

  char* ws = (char*)d_ws;
  size_t off = 0;
  auto carve = [&](size_t bytes) {
    char* p = ws + off;
    off += (bytes + 255) & ~(size_t)255;
    return p;
  };
  _Float16* x16     = (_Float16*)carve((size_t)MROWS * NIN * 2);  // 8MB
  _Float16* wih0_16 = (_Float16*)carve((size_t)H * NIN * 2);
  _Float16* whh0_16 = (_Float16*)carve((size_t)H * H * 2);
  _Float16* wih1_16 = (_Float16*)carve((size_t)H * H * 2);
  _Float16* whh1_16 = (_Float16*)carve((size_t)H * H * 2);
  float*    bias0   = (float*)   carve(H * 4);
  float*    bias1   = (float*)   carve(H * 4);
  // zero region: [f0 | s0 | f1 | s1 | progress] contiguous
  u64*      f0      = (u64*)     carve((size_t)NCLUST * D0 * UNITS * 8);
  u64*      s0      = (u64*)     carve((size_t)NCLUST * D0 * UNITS * 8);
  u64*      f1      = (u64*)     carve((size_t)NCLUST * D1 * UNITS * 8);
  u64*      s1      = (u64*)     carve((size_t)NCLUST * D1 * UNITS * 8);
  unsigned* progress= (unsigned*)carve((size_t)NCLUST * 64 * 4);
  float*    h_lastp = (float*)   carve((size_t)BATCH * H * 4);

  const int zero_words =
      (int)(((size_t)NCLUST * (D0 + D0 + D1 + D1) * UNITS * 8 +
             (size_t)NCLUST * 64 * 4) / 4);

  init_misc_kernel<<<(zero_words + 255) / 256, 256, 0, stream>>>(
      b_ih0, b_hh0, b_ih1, b_hh1, bias0, bias1, (unsigned*)f0, zero_words);

  cvt16_kernel<<<(MROWS * NIN / 4 + 255) / 256, 256, 0, stream>>>(
      x, x16, MROWS * NIN / 4);
  cvt16_kernel<<<(H * NIN / 4 + 255) / 256, 256, 0, stream>>>(
      W_ih0, wih0_16, H * NIN / 4);
  cvt16_kernel<<<(H * H / 4 + 255) / 256, 256, 0, stream>>>(
      W_hh0, whh0_16, H * H / 4);
  cvt16_kernel<<<(H * H / 4 + 255) / 256, 256, 0, stream>>>(
      W_ih1, wih1_16, H * H / 4);
  cvt16_kernel<<<(H * H / 4 + 255) / 256, 256, 0, stream>>>(
      W_hh1, whh1_16, H * H / 4);

  // fused two-layer scan (256 blocks x 256 thr, cooperative)
  {
    const _Float16* x_p = x16;
    const _Float16* wi0 = wih0_16; const _Float16* wh0 = whh0_16;
    const _Float16* wi1 = wih1_16; const _Float16* wh1 = whh1_16;
    const float* bz0 = bias0; const float* bz1 = bias1;
    u64* f0p = f0; u64* s0p = s0; u64* f1p = f1; u64* s1p = s1;
    unsigned* pr = progress; float* hl = h_lastp;
    void* args[] = {&x_p, &wi0, &wh0, &wi1, &wh1, &bz0, &bz1,
                    &f0p, &s0p, &f1p, &s1p, &pr, &hl};
    hipLaunchCooperativeKernel((const void*)fused_scan_kernel, dim3(256),
                               dim3(256), args, 0, stream);
  }

  fc_kernel<<<BATCH * NOUT / 4, 256, 0, stream>>>(h_lastp, W_fc, b_fc, out);
}